// Round 16
// baseline (290.525 us; speedup 1.0000x reference)
//
#include <hip/hip_runtime.h>

typedef __bf16 bf16_t;
typedef __bf16 bf16x8 __attribute__((ext_vector_type(8)));
typedef float f32x4 __attribute__((ext_vector_type(4)));
typedef float f32x16 __attribute__((ext_vector_type(16)));

#define MFMA16(a, b, c) __builtin_amdgcn_mfma_f32_16x16x32_bf16(a, b, c, 0, 0, 0)
#define MFMA32(a, b, c) __builtin_amdgcn_mfma_f32_32x32x16_bf16(a, b, c, 0, 0, 0)

#define F_W 128
#define ED 512
#define NH 8
#define HD 64
#define NTOK 65536

typedef const __attribute__((address_space(1))) void gvoid_t;
typedef __attribute__((address_space(3))) void lvoid_t;
__device__ __forceinline__ void gload16(const void* g, void* l) {
    __builtin_amdgcn_global_load_lds((gvoid_t*)g, (lvoid_t*)l, 16, 0, 0);
}

// swizzle for [row][32] bf16 tiles (64B rows); 16-row b128 reads = 0 conflicts
__device__ __forceinline__ int swz32(int row) { return ((row >> 1) & 3) << 3; }

// ---------------- prep (merged): x->bf16 + weights->bf16 transposed ---------
__global__ __launch_bounds__(256) void prep_all_kernel(
    const float* __restrict__ x,       // [NTOK][512]
    const float* __restrict__ qkv_w,   // [512][1536]
    const float* __restrict__ proj_w,  // [512][512]
    bf16_t* __restrict__ xbf,          // [NTOK][512]
    bf16_t* __restrict__ qkv_wt,       // [1536][512]
    bf16_t* __restrict__ proj_wt) {    // [512][512]
    int gid = blockIdx.x * 256 + threadIdx.x;
    size_t i = (size_t)gid * 8;
    float4 v0 = *(const float4*)(x + i);
    float4 v1 = *(const float4*)(x + i + 4);
    bf16x8 o = {(bf16_t)v0.x, (bf16_t)v0.y, (bf16_t)v0.z, (bf16_t)v0.w,
                (bf16_t)v1.x, (bf16_t)v1.y, (bf16_t)v1.z, (bf16_t)v1.w};
    *(bf16x8*)(xbf + i) = o;
    if (gid < 1536 * 512) {
        int n = gid >> 9, k = gid & 511;
        qkv_wt[gid] = (bf16_t)qkv_w[k * 1536 + n];
    }
    if (gid < 512 * 512) {
        int n = gid >> 9, k = gid & 511;
        proj_wt[gid] = (bf16_t)proj_w[k * 512 + n];
    }
}

// ---------------- K2: QKV GEMM [65536,512]x[512,1536] (r10 base) ------------
// 128x128 tiles, 2x2 wave grid (wave 64x64), 32x32x16 MFMA, BK=64,
// single-buffered [128][64]-swz8 tiles (32 KB), 8 K-steps, 4 blocks/CU.
// tb bounce re-padded 72->80 (conflict-source experiment).
__global__ __launch_bounds__(256, 4) void qkv_gemm_kernel(
    const bf16_t* __restrict__ xbf,     // [NTOK][512] bf16
    const bf16_t* __restrict__ qkv_wt,  // [1536][512] bf16 (n-major)
    const float* __restrict__ qkv_b,    // [1536]
    bf16_t* qk_ws,                      // [NTOK][1024]  Q(scaled)|K
    bf16_t* vt_ws) {                    // [4096][64][128]  V^T per (w,h)
    __shared__ __align__(16) char sm[32768];
    bf16_t* x_s = (bf16_t*)sm;              // [128][64] swz8
    bf16_t* w_s = (bf16_t*)(sm + 16384);    // [128][64] swz8
    bf16_t* tb  = (bf16_t*)sm;              // [128][80] epilogue bounce (aliases)

    const int tid = threadIdx.x;
    const int wave = tid >> 6, lane = tid & 63;
    const int l31 = lane & 31, lhi = lane >> 5;
    const int wm = wave >> 1, wn = wave & 1;
    const int bid = blockIdx.x;
    const int idx = bid >> 3;
    const int mt_l = idx / 12;
    const int nt = idx - mt_l * 12;
    const int mtile = (bid & 7) * 64 + mt_l;   // == window index
    const size_t m0 = (size_t)mtile * 128;
    const int n0 = nt * 128;

    // staging: 1KB chunk = 8 rows x 64 bf16; lane -> row lane>>3, col (lane&7)*8
    const int srow = lane >> 3;
    const int scol = ((lane & 7) * 8) ^ ((srow & 7) << 3);  // preswizzled src col

    f32x16 acc[2][2];
#pragma unroll
    for (int mf = 0; mf < 2; ++mf)
#pragma unroll
        for (int nf = 0; nf < 2; ++nf) acc[mf][nf] = (f32x16)0.0f;

    for (int kc = 0; kc < 8; ++kc) {
        const int k0 = kc * 64;
        __syncthreads();   // previous compute's reads done
#pragma unroll
        for (int i = 0; i < 4; ++i) {  // x: 16 chunks of 8 rows
            int c = wave * 4 + i;
            gload16(xbf + (m0 + c * 8 + srow) * 512 + k0 + scol, x_s + c * 512);
        }
#pragma unroll
        for (int i = 0; i < 4; ++i) {  // w: 16 chunks of 8 rows
            int c = wave * 4 + i;
            gload16(qkv_wt + (size_t)(n0 + c * 8 + srow) * 512 + k0 + scol,
                    w_s + c * 512);
        }
        __syncthreads();   // staged data visible

#pragma unroll
        for (int ks = 0; ks < 4; ++ks) {  // 4 x (K=16)
            bf16x8 a[2], b[2];
#pragma unroll
            for (int mf = 0; mf < 2; ++mf) {
                int row = wm * 64 + mf * 32 + l31;
                a[mf] = *(const bf16x8*)(x_s + row * 64 +
                                         ((ks * 16 + lhi * 8) ^ ((row & 7) << 3)));
            }
#pragma unroll
            for (int nf = 0; nf < 2; ++nf) {
                int rw = wn * 64 + nf * 32 + l31;
                b[nf] = *(const bf16x8*)(w_s + rw * 64 +
                                         ((ks * 16 + lhi * 8) ^ ((rw & 7) << 3)));
            }
#pragma unroll
            for (int mf = 0; mf < 2; ++mf)
#pragma unroll
                for (int nf = 0; nf < 2; ++nf)
                    acc[mf][nf] = MFMA32(a[mf], b[nf], acc[mf][nf]);
        }
    }

    if (nt < 8) {
        // Q or K tile: bias, scale Q, row-major bf16 to qk_ws
        // D layout (32x32): col = lane&31, row = (j&3) + 8*(j>>2) + 4*(lane>>5)
        const float scale = (nt < 4) ? 0.125f : 1.0f;
#pragma unroll
        for (int nf = 0; nf < 2; ++nf) {
            int col = n0 + wn * 64 + nf * 32 + l31;    // [0,1024)
            float bv = qkv_b[col];
#pragma unroll
            for (int mf = 0; mf < 2; ++mf)
#pragma unroll
                for (int j = 0; j < 16; ++j) {
                    int r = wm * 64 + mf * 32 + (j & 3) + 8 * (j >> 2) + 4 * lhi;
                    qk_ws[(m0 + r) * 1024 + col] =
                        (bf16_t)((acc[mf][nf][j] + bv) * scale);
                }
        }
    } else {
        // V tile: wave wn owns head (nt-8)*2 + wn (cols wn*64..+63 of tile)
#pragma unroll
        for (int hh = 0; hh < 2; ++hh) {
            int h = (nt - 8) * 2 + hh;
            __syncthreads();   // prior sm reads (or prior tb pass) complete
            if (wn == hh) {
#pragma unroll
                for (int nf = 0; nf < 2; ++nf) {
                    int d = nf * 32 + l31;             // [0,64)
                    float bv = qkv_b[n0 + hh * 64 + d];
#pragma unroll
                    for (int mf = 0; mf < 2; ++mf)
#pragma unroll
                        for (int j = 0; j < 16; ++j) {
                            int r = wm * 64 + mf * 32 + (j & 3) + 8 * (j >> 2) + 4 * lhi;
                            tb[r * 80 + d] = (bf16_t)(acc[mf][nf][j] + bv);
                        }
                }
            }
            __syncthreads();
            // transpose-read, coalesced write: vt_ws[(mtile*8+h)][d][k]
            {
                int d = tid & 63;
                int kh = tid >> 6;                     // k range kh*32
                bf16_t* outp = vt_ws + ((size_t)(mtile * 8 + h) * 64 + d) * 128 + kh * 32;
#pragma unroll
                for (int o = 0; o < 4; ++o) {
                    bf16x8 v;
#pragma unroll
                    for (int e = 0; e < 8; ++e)
                        v[e] = tb[(kh * 32 + o * 8 + e) * 80 + d];
                    *(bf16x8*)(outp + o * 8) = v;
                }
            }
        }
    }
}

// ---------------- K3: attention-only, block=(window,head), 512 thr ----------
// 48 KB plan: k_lds [0,16K) dies after QK^T; vt_lds [16K,32K) persists;
// full P = p0 [0,16K) (cols 0..63, aliases k_lds) + p1 [32K,48K) (cols 64..127).
// 3 barriers total; PV runs 4 K-steps uninterrupted.
__global__ __launch_bounds__(512, 4) void attn_kernel(
    bf16_t* qk_ws,                      // [NTOK][1024] (Q|K; O -> Q cols)
    const bf16_t* __restrict__ vt_ws,   // [4096][64][128]
    const float* __restrict__ adj) {    // [8][8][128][128]
    __shared__ __align__(16) char sm[49152];
    bf16_t* k_lds  = (bf16_t*)sm;             // [128][64] swz8
    bf16_t* vt_lds = (bf16_t*)(sm + 16384);   // [64][128] swz8-col
    bf16_t* p0     = (bf16_t*)sm;             // [128][64] swz8 (aliases k_lds)
    bf16_t* p1     = (bf16_t*)(sm + 32768);   // [128][64] swz8

    const int tid = threadIdx.x;
    const int wave = tid >> 6, lane = tid & 63;
    const int lrow = lane & 15, lgrp = lane >> 4;
    const int bid = blockIdx.x;
    const int w = (bid & 7) * 64 + (bid >> 6);
    const int h = (bid >> 3) & 7;
    const int bidx = bid & 7;

    bf16_t* qrow = qk_ws + (size_t)w * 128 * 1024;

    {
        const int krow_l = lane >> 3;
        const int kcol_l = ((lane & 7) * 8) ^ ((krow_l & 7) << 3);
#pragma unroll
        for (int i = 0; i < 2; ++i) {
            int c = wave * 2 + i;
            gload16(qrow + (size_t)(c * 8 + krow_l) * 1024 + 512 + h * 64 + kcol_l,
                    k_lds + c * 512);
        }
    }
    {
        const bf16_t* vtb = vt_ws + (size_t)(w * 8 + h) * 64 * 128;
        const int vrow_l = lane >> 4;
#pragma unroll
        for (int i = 0; i < 2; ++i) {
            int c = wave * 2 + i;
            int d = c * 4 + vrow_l;
            int vcol = ((lane & 15) * 8) ^ ((d & 7) << 3);
            gload16(vtb + (size_t)d * 128 + vcol, vt_lds + c * 512);
        }
    }
    bf16x8 aq[2];
    {
        int row = wave * 16 + lrow;
#pragma unroll
        for (int kb = 0; kb < 2; ++kb)
            aq[kb] = *(const bf16x8*)(qrow + (size_t)row * 1024 + h * 64 + kb * 32 + lgrp * 8);
    }
    __syncthreads();   // barrier 1: staging complete

    f32x4 sacc[8];
#pragma unroll
    for (int nf = 0; nf < 8; ++nf) sacc[nf] = (f32x4)0.0f;
#pragma unroll
    for (int kb = 0; kb < 2; ++kb) {
        bf16x8 b[8];
#pragma unroll
        for (int nf = 0; nf < 8; ++nf) {
            int row = nf * 16 + lrow;
            b[nf] = *(const bf16x8*)(k_lds + row * 64 + ((kb * 32 + lgrp * 8) ^ ((row & 7) << 3)));
        }
#pragma unroll
        for (int nf = 0; nf < 8; ++nf)
            sacc[nf] = MFMA16(aq[kb], b[nf], sacc[nf]);
    }

    const float* mbase = adj + ((size_t)(bidx * NH + h)) * F_W * F_W;
#pragma unroll
    for (int j = 0; j < 4; ++j) {
        int row = wave * 16 + lgrp * 4 + j;
        const float* mrow = mbase + (size_t)row * F_W;
        float mx = -1e30f;
#pragma unroll
        for (int nf = 0; nf < 8; ++nf) {
            sacc[nf][j] += mrow[nf * 16 + lrow];
            mx = fmaxf(mx, sacc[nf][j]);
        }
#pragma unroll
        for (int d = 1; d < 16; d <<= 1) mx = fmaxf(mx, __shfl_xor(mx, d));
        float sum = 0.f;
#pragma unroll
        for (int nf = 0; nf < 8; ++nf) {
            float p = exp2f((sacc[nf][j] - mx) * 1.44269504f);
            sacc[nf][j] = p;
            sum += p;
        }
#pragma unroll
        for (int d = 1; d < 16; d <<= 1) sum += __shfl_xor(sum, d);
        float r = 1.0f / sum;
#pragma unroll
        for (int nf = 0; nf < 8; ++nf) sacc[nf][j] *= r;
    }
    __syncthreads();   // barrier 2: all QK^T reads of k_lds done -> P may alias

    // write full P: cols 0..63 -> p0, cols 64..127 -> p1 (swz8, 16-row pattern)
#pragma unroll
    for (int nf = 0; nf < 8; ++nf) {
        int col = nf * 16 + lrow;          // [0,128)
        bf16_t* pr = (col < 64) ? p0 : p1;
        int c = col & 63;
#pragma unroll
        for (int j = 0; j < 4; ++j) {
            int r = wave * 16 + lgrp * 4 + j;
            pr[r * 64 + (c ^ ((r & 7) << 3))] = (bf16_t)(sacc[nf][j]);
        }
    }
    __syncthreads();   // barrier 3: P visible

    f32x4 oacc[4];
#pragma unroll
    for (int nf = 0; nf < 4; ++nf) oacc[nf] = (f32x4)0.0f;

#pragma unroll
    for (int kb = 0; kb < 4; ++kb) {       // no barriers inside PV
        bf16_t* pr = (kb < 2) ? p0 : p1;
        int arow = wave * 16 + lrow;
        bf16x8 a = *(const bf16x8*)(pr + arow * 64 +
                                    (((kb & 1) * 32 + lgrp * 8) ^ ((arow & 7) << 3)));
        bf16x8 b[4];
#pragma unroll
        for (int nf = 0; nf < 4; ++nf) {
            int d = nf * 16 + lrow;
            b[nf] = *(const bf16x8*)(vt_lds + d * 128 + ((kb * 32 + lgrp * 8) ^ ((d & 7) << 3)));
        }
#pragma unroll
        for (int nf = 0; nf < 4; ++nf)
            oacc[nf] = MFMA16(a, b[nf], oacc[nf]);
    }

#pragma unroll
    for (int nf = 0; nf < 4; ++nf) {
        int ocol = h * 64 + nf * 16 + lrow;
#pragma unroll
        for (int j = 0; j < 4; ++j) {
            int r = wave * 16 + lgrp * 4 + j;
            qrow[(size_t)r * 1024 + ocol] = (bf16_t)oacc[nf][j];
        }
    }
}

// ---------------- K4: output projection (r10, best) -------------------------
// 128-tile, 32x32x16 MFMA, [128][64]-swz8, BK=64 single-buffered.
__global__ __launch_bounds__(256, 4) void proj_kernel(
    const bf16_t* __restrict__ a_g,   // [NTOK][1024] (cols 0..511 = O)
    const bf16_t* __restrict__ bt_g,  // proj_wt [512][512] (n-major)
    const float* __restrict__ bias,   // [512]
    float* __restrict__ out) {        // [NTOK][512] fp32
    __shared__ __align__(16) char sm_[32768];
    bf16_t* a_s = (bf16_t*)sm_;             // [128][64] swz8
    bf16_t* b_s = (bf16_t*)(sm_ + 16384);   // [128][64] swz8
    const int tid = threadIdx.x;
    const int wave = tid >> 6, lane = tid & 63;
    const int l31 = lane & 31, lhi = lane >> 5;
    const int wm = wave >> 1, wn = wave & 1;
    const int bid = blockIdx.x;                        // [0,2048)
    const int mtile = (bid & 7) * 64 + (bid >> 5);
    const int ntile = (bid >> 3) & 3;
    const size_t m0 = (size_t)mtile * 128;
    const int n0 = ntile * 128;
    const int srow = lane >> 3;
    const int scol = ((lane & 7) * 8) ^ ((srow & 7) << 3);

    f32x16 acc[2][2];
#pragma unroll
    for (int mf = 0; mf < 2; ++mf)
#pragma unroll
        for (int nf = 0; nf < 2; ++nf) acc[mf][nf] = (f32x16)0.0f;

    for (int kc = 0; kc < 8; ++kc) {
        const int k0 = kc * 64;
        __syncthreads();
#pragma unroll
        for (int i = 0; i < 4; ++i) {
            int c = wave * 4 + i;
            gload16(a_g + (m0 + c * 8 + srow) * 1024 + k0 + scol, a_s + c * 512);
            gload16(bt_g + (size_t)(n0 + c * 8 + srow) * 512 + k0 + scol, b_s + c * 512);
        }
        __syncthreads();

#pragma unroll
        for (int ks = 0; ks < 4; ++ks) {
            bf16x8 a[2], b[2];
#pragma unroll
            for (int mf = 0; mf < 2; ++mf) {
                int row = wm * 64 + mf * 32 + l31;
                a[mf] = *(const bf16x8*)(a_s + row * 64 +
                                         ((ks * 16 + lhi * 8) ^ ((row & 7) << 3)));
            }
#pragma unroll
            for (int nf = 0; nf < 2; ++nf) {
                int rw = wn * 64 + nf * 32 + l31;
                b[nf] = *(const bf16x8*)(b_s + rw * 64 +
                                         ((ks * 16 + lhi * 8) ^ ((rw & 7) << 3)));
            }
#pragma unroll
            for (int mf = 0; mf < 2; ++mf)
#pragma unroll
                for (int nf = 0; nf < 2; ++nf)
                    acc[mf][nf] = MFMA32(a[mf], b[nf], acc[mf][nf]);
        }
    }

#pragma unroll
    for (int nf = 0; nf < 2; ++nf) {
        int col = n0 + wn * 64 + nf * 32 + l31;
        float bv = bias[col];
#pragma unroll
        for (int mf = 0; mf < 2; ++mf)
#pragma unroll
            for (int j = 0; j < 16; ++j) {
                size_t row = m0 + wm * 64 + mf * 32 + (j & 3) + 8 * (j >> 2) + 4 * lhi;
                out[row * 512 + col] = acc[mf][nf][j] + bv;
            }
    }
}

extern "C" void kernel_launch(void* const* d_in, const int* in_sizes, int n_in,
                              void* d_out, int out_size, void* d_ws, size_t ws_size,
                              hipStream_t stream) {
    const float* x      = (const float*)d_in[0];
    const float* adj    = (const float*)d_in[1];
    const float* qkv_w  = (const float*)d_in[2];
    const float* qkv_b  = (const float*)d_in[3];
    const float* proj_w = (const float*)d_in[4];
    const float* proj_b = (const float*)d_in[5];
    float* out = (float*)d_out;

    // ws: qk_ws 134.2MB | vt_ws 67.1MB | qkv_wt 1.5MB | proj_wt 0.5MB
    bf16_t* qk_ws   = (bf16_t*)d_ws;
    bf16_t* vt_ws   = qk_ws + (size_t)NTOK * 1024;
    bf16_t* qkv_wt  = vt_ws + (size_t)4096 * 64 * 128;
    bf16_t* proj_wt = qkv_wt + 1536 * 512;
    // x-bf16 lives in d_out (64MB of its 128MB); proj overwrites d_out last.
    bf16_t* xbf = (bf16_t*)d_out;

    prep_all_kernel<<<NTOK * ED / 8 / 256, 256, 0, stream>>>(
        x, qkv_w, proj_w, xbf, qkv_wt, proj_wt);
    qkv_gemm_kernel<<<6144, 256, 0, stream>>>(xbf, qkv_wt, qkv_b, qk_ws, vt_ws);
    attn_kernel<<<4096, 512, 0, stream>>>(qk_ws, vt_ws, adj);
    proj_kernel<<<2048, 256, 0, stream>>>(qk_ws, proj_wt, proj_b, out);
}

// Round 17
// 287.264 us; speedup vs baseline: 1.0113x; 1.0113x over previous
//
#include <hip/hip_runtime.h>

typedef __bf16 bf16_t;
typedef __bf16 bf16x8 __attribute__((ext_vector_type(8)));
typedef float f32x4 __attribute__((ext_vector_type(4)));
typedef float f32x16 __attribute__((ext_vector_type(16)));

#define MFMA16(a, b, c) __builtin_amdgcn_mfma_f32_16x16x32_bf16(a, b, c, 0, 0, 0)
#define MFMA32(a, b, c) __builtin_amdgcn_mfma_f32_32x32x16_bf16(a, b, c, 0, 0, 0)

#define F_W 128
#define ED 512
#define NH 8
#define HD 64
#define NTOK 65536

typedef const __attribute__((address_space(1))) void gvoid_t;
typedef __attribute__((address_space(3))) void lvoid_t;
__device__ __forceinline__ void gload16(const void* g, void* l) {
    __builtin_amdgcn_global_load_lds((gvoid_t*)g, (lvoid_t*)l, 16, 0, 0);
}

// swizzle for [row][32] bf16 tiles (64B rows); 16-row b128 reads = 0 conflicts
__device__ __forceinline__ int swz32(int row) { return ((row >> 1) & 3) << 3; }

// ---------------- prep (merged): x->bf16 + weights->bf16 transposed ---------
__global__ __launch_bounds__(256) void prep_all_kernel(
    const float* __restrict__ x,       // [NTOK][512]
    const float* __restrict__ qkv_w,   // [512][1536]
    const float* __restrict__ proj_w,  // [512][512]
    bf16_t* __restrict__ xbf,          // [NTOK][512]
    bf16_t* __restrict__ qkv_wt,       // [1536][512]
    bf16_t* __restrict__ proj_wt) {    // [512][512]
    int gid = blockIdx.x * 256 + threadIdx.x;
    size_t i = (size_t)gid * 8;
    float4 v0 = *(const float4*)(x + i);
    float4 v1 = *(const float4*)(x + i + 4);
    bf16x8 o = {(bf16_t)v0.x, (bf16_t)v0.y, (bf16_t)v0.z, (bf16_t)v0.w,
                (bf16_t)v1.x, (bf16_t)v1.y, (bf16_t)v1.z, (bf16_t)v1.w};
    *(bf16x8*)(xbf + i) = o;
    if (gid < 1536 * 512) {
        int n = gid >> 9, k = gid & 511;
        qkv_wt[gid] = (bf16_t)qkv_w[k * 1536 + n];
    }
    if (gid < 512 * 512) {
        int n = gid >> 9, k = gid & 511;
        proj_wt[gid] = (bf16_t)proj_w[k * 512 + n];
    }
}

// ---------------- K2: QKV GEMM [65536,512]x[512,1536] (r10 best config) -----
// 128x128 tiles, 2x2 wave grid (wave 64x64), 32x32x16 MFMA, BK=64,
// single-buffered [128][64]-swz8 tiles (32 KB), 8 K-steps (fully unrolled),
// 4 blocks/CU. n-tiles 0..3 -> Q (x0.125), 4..7 -> K, 8..11 -> V.
__global__ __launch_bounds__(256, 4) void qkv_gemm_kernel(
    const bf16_t* __restrict__ xbf,     // [NTOK][512] bf16
    const bf16_t* __restrict__ qkv_wt,  // [1536][512] bf16 (n-major)
    const float* __restrict__ qkv_b,    // [1536]
    bf16_t* qk_ws,                      // [NTOK][1024]  Q(scaled)|K
    bf16_t* vt_ws) {                    // [4096][64][128]  V^T per (w,h)
    __shared__ __align__(16) char sm[32768];
    bf16_t* x_s = (bf16_t*)sm;              // [128][64] swz8
    bf16_t* w_s = (bf16_t*)(sm + 16384);    // [128][64] swz8
    bf16_t* tb  = (bf16_t*)sm;              // [128][80] epilogue bounce (aliases)

    const int tid = threadIdx.x;
    const int wave = tid >> 6, lane = tid & 63;
    const int l31 = lane & 31, lhi = lane >> 5;
    const int wm = wave >> 1, wn = wave & 1;
    const int bid = blockIdx.x;
    const int idx = bid >> 3;
    const int mt_l = idx / 12;
    const int nt = idx - mt_l * 12;
    const int mtile = (bid & 7) * 64 + mt_l;   // == window index
    const size_t m0 = (size_t)mtile * 128;
    const int n0 = nt * 128;

    // staging: 1KB chunk = 8 rows x 64 bf16; lane -> row lane>>3, col (lane&7)*8
    const int srow = lane >> 3;
    const int scol = ((lane & 7) * 8) ^ ((srow & 7) << 3);  // preswizzled src col

    f32x16 acc[2][2];
#pragma unroll
    for (int mf = 0; mf < 2; ++mf)
#pragma unroll
        for (int nf = 0; nf < 2; ++nf) acc[mf][nf] = (f32x16)0.0f;

#pragma unroll
    for (int kc = 0; kc < 8; ++kc) {
        const int k0 = kc * 64;
        __syncthreads();   // previous compute's reads done
#pragma unroll
        for (int i = 0; i < 4; ++i) {  // x: 16 chunks of 8 rows
            int c = wave * 4 + i;
            gload16(xbf + (m0 + c * 8 + srow) * 512 + k0 + scol, x_s + c * 512);
        }
#pragma unroll
        for (int i = 0; i < 4; ++i) {  // w: 16 chunks of 8 rows
            int c = wave * 4 + i;
            gload16(qkv_wt + (size_t)(n0 + c * 8 + srow) * 512 + k0 + scol,
                    w_s + c * 512);
        }
        __syncthreads();   // staged data visible

#pragma unroll
        for (int ks = 0; ks < 4; ++ks) {  // 4 x (K=16)
            bf16x8 a[2], b[2];
#pragma unroll
            for (int mf = 0; mf < 2; ++mf) {
                int row = wm * 64 + mf * 32 + l31;
                a[mf] = *(const bf16x8*)(x_s + row * 64 +
                                         ((ks * 16 + lhi * 8) ^ ((row & 7) << 3)));
            }
#pragma unroll
            for (int nf = 0; nf < 2; ++nf) {
                int rw = wn * 64 + nf * 32 + l31;
                b[nf] = *(const bf16x8*)(w_s + rw * 64 +
                                         ((ks * 16 + lhi * 8) ^ ((rw & 7) << 3)));
            }
#pragma unroll
            for (int mf = 0; mf < 2; ++mf)
#pragma unroll
                for (int nf = 0; nf < 2; ++nf)
                    acc[mf][nf] = MFMA32(a[mf], b[nf], acc[mf][nf]);
        }
    }

    if (nt < 8) {
        // Q or K tile: bias, scale Q, row-major bf16 to qk_ws
        // D layout (32x32): col = lane&31, row = (j&3) + 8*(j>>2) + 4*(lane>>5)
        const float scale = (nt < 4) ? 0.125f : 1.0f;
#pragma unroll
        for (int nf = 0; nf < 2; ++nf) {
            int col = n0 + wn * 64 + nf * 32 + l31;    // [0,1024)
            float bv = qkv_b[col];
#pragma unroll
            for (int mf = 0; mf < 2; ++mf)
#pragma unroll
                for (int j = 0; j < 16; ++j) {
                    int r = wm * 64 + mf * 32 + (j & 3) + 8 * (j >> 2) + 4 * lhi;
                    qk_ws[(m0 + r) * 1024 + col] =
                        (bf16_t)((acc[mf][nf][j] + bv) * scale);
                }
        }
    } else {
        // V tile: wave wn owns head (nt-8)*2 + wn (cols wn*64..+63 of tile)
#pragma unroll
        for (int hh = 0; hh < 2; ++hh) {
            int h = (nt - 8) * 2 + hh;
            __syncthreads();   // prior sm reads (or prior tb pass) complete
            if (wn == hh) {
#pragma unroll
                for (int nf = 0; nf < 2; ++nf) {
                    int d = nf * 32 + l31;             // [0,64)
                    float bv = qkv_b[n0 + hh * 64 + d];
#pragma unroll
                    for (int mf = 0; mf < 2; ++mf)
#pragma unroll
                        for (int j = 0; j < 16; ++j) {
                            int r = wm * 64 + mf * 32 + (j & 3) + 8 * (j >> 2) + 4 * lhi;
                            tb[r * 80 + d] = (bf16_t)(acc[mf][nf][j] + bv);
                        }
                }
            }
            __syncthreads();
            // transpose-read, coalesced write: vt_ws[(mtile*8+h)][d][k]
            {
                int d = tid & 63;
                int kh = tid >> 6;                     // k range kh*32
                bf16_t* outp = vt_ws + ((size_t)(mtile * 8 + h) * 64 + d) * 128 + kh * 32;
#pragma unroll
                for (int o = 0; o < 4; ++o) {
                    bf16x8 v;
#pragma unroll
                    for (int e = 0; e < 8; ++e)
                        v[e] = tb[(kh * 32 + o * 8 + e) * 80 + d];
                    *(bf16x8*)(outp + o * 8) = v;
                }
            }
        }
    }
}

// ---------------- K3: attention-only (r15 ping-pong version, best) ----------
__global__ __launch_bounds__(512, 4) void attn_kernel(
    bf16_t* qk_ws,                      // [NTOK][1024] (Q|K; O -> Q cols)
    const bf16_t* __restrict__ vt_ws,   // [4096][64][128]
    const float* __restrict__ adj) {    // [8][8][128][128]
    __shared__ __align__(16) char sm[32768];
    bf16_t* k_lds  = (bf16_t*)sm;             // [128][64]
    bf16_t* vt_lds = (bf16_t*)(sm + 16384);   // [64][128]
    bf16_t* pb0    = (bf16_t*)sm;             // [128][32] swz32 (aliases k)
    bf16_t* pb1    = (bf16_t*)(sm + 8192);    // [128][32] swz32

    const int tid = threadIdx.x;
    const int wave = tid >> 6, lane = tid & 63;
    const int lrow = lane & 15, lgrp = lane >> 4;
    const int bid = blockIdx.x;
    const int w = (bid & 7) * 64 + (bid >> 6);
    const int h = (bid >> 3) & 7;
    const int bidx = bid & 7;

    bf16_t* qrow = qk_ws + (size_t)w * 128 * 1024;

    {
        const int krow_l = lane >> 3;
        const int kcol_l = ((lane & 7) * 8) ^ ((krow_l & 7) << 3);
#pragma unroll
        for (int i = 0; i < 2; ++i) {
            int c = wave * 2 + i;
            gload16(qrow + (size_t)(c * 8 + krow_l) * 1024 + 512 + h * 64 + kcol_l,
                    k_lds + c * 512);
        }
    }
    {
        const bf16_t* vtb = vt_ws + (size_t)(w * 8 + h) * 64 * 128;
        const int vrow_l = lane >> 4;
#pragma unroll
        for (int i = 0; i < 2; ++i) {
            int c = wave * 2 + i;
            int d = c * 4 + vrow_l;
            int vcol = ((lane & 15) * 8) ^ ((d & 7) << 3);
            gload16(vtb + (size_t)d * 128 + vcol, vt_lds + c * 512);
        }
    }
    bf16x8 aq[2];
    {
        int row = wave * 16 + lrow;
#pragma unroll
        for (int kb = 0; kb < 2; ++kb)
            aq[kb] = *(const bf16x8*)(qrow + (size_t)row * 1024 + h * 64 + kb * 32 + lgrp * 8);
    }
    __syncthreads();

    f32x4 sacc[8];
#pragma unroll
    for (int nf = 0; nf < 8; ++nf) sacc[nf] = (f32x4)0.0f;
#pragma unroll
    for (int kb = 0; kb < 2; ++kb) {
        bf16x8 b[8];
#pragma unroll
        for (int nf = 0; nf < 8; ++nf) {
            int row = nf * 16 + lrow;
            b[nf] = *(const bf16x8*)(k_lds + row * 64 + ((kb * 32 + lgrp * 8) ^ ((row & 7) << 3)));
        }
#pragma unroll
        for (int nf = 0; nf < 8; ++nf)
            sacc[nf] = MFMA16(aq[kb], b[nf], sacc[nf]);
    }

    const float* mbase = adj + ((size_t)(bidx * NH + h)) * F_W * F_W;
#pragma unroll
    for (int j = 0; j < 4; ++j) {
        int row = wave * 16 + lgrp * 4 + j;
        const float* mrow = mbase + (size_t)row * F_W;
        float mx = -1e30f;
#pragma unroll
        for (int nf = 0; nf < 8; ++nf) {
            sacc[nf][j] += mrow[nf * 16 + lrow];
            mx = fmaxf(mx, sacc[nf][j]);
        }
#pragma unroll
        for (int d = 1; d < 16; d <<= 1) mx = fmaxf(mx, __shfl_xor(mx, d));
        float sum = 0.f;
#pragma unroll
        for (int nf = 0; nf < 8; ++nf) {
            float p = exp2f((sacc[nf][j] - mx) * 1.44269504f);
            sacc[nf][j] = p;
            sum += p;
        }
#pragma unroll
        for (int d = 1; d < 16; d <<= 1) sum += __shfl_xor(sum, d);
        float r = 1.0f / sum;
#pragma unroll
        for (int nf = 0; nf < 8; ++nf) sacc[nf][j] *= r;
    }
    __syncthreads();   // k_lds dead; pb0/pb1 may be written

    // write P chunk 0 (K cols 0..31) into pb0
#pragma unroll
    for (int nn = 0; nn < 2; ++nn) {
        int kk = nn * 16 + lrow;
#pragma unroll
        for (int j = 0; j < 4; ++j) {
            int r = wave * 16 + lgrp * 4 + j;
            pb0[r * 32 + (kk ^ swz32(r))] = (bf16_t)(sacc[nn][j]);
        }
    }
    __syncthreads();

    f32x4 oacc[4];
#pragma unroll
    for (int nf = 0; nf < 4; ++nf) oacc[nf] = (f32x4)0.0f;

#pragma unroll
    for (int kb = 0; kb < 4; ++kb) {
        bf16_t* pcur = (kb & 1) ? pb1 : pb0;
        bf16_t* pnxt = (kb & 1) ? pb0 : pb1;
        int arow = wave * 16 + lrow;
        bf16x8 a = *(const bf16x8*)(pcur + arow * 32 + ((lgrp * 8) ^ swz32(arow)));
        if (kb < 3) {
#pragma unroll
            for (int nn = 0; nn < 2; ++nn) {
                int nf = (kb + 1) * 2 + nn;
                int kk = nn * 16 + lrow;
#pragma unroll
                for (int j = 0; j < 4; ++j) {
                    int r = wave * 16 + lgrp * 4 + j;
                    pnxt[r * 32 + (kk ^ swz32(r))] = (bf16_t)(sacc[nf][j]);
                }
            }
        }
        bf16x8 b[4];
#pragma unroll
        for (int nf = 0; nf < 4; ++nf) {
            int d = nf * 16 + lrow;
            b[nf] = *(const bf16x8*)(vt_lds + d * 128 + ((kb * 32 + lgrp * 8) ^ ((d & 7) << 3)));
        }
#pragma unroll
        for (int nf = 0; nf < 4; ++nf)
            oacc[nf] = MFMA16(a, b[nf], oacc[nf]);
        __syncthreads();
    }

#pragma unroll
    for (int nf = 0; nf < 4; ++nf) {
        int ocol = h * 64 + nf * 16 + lrow;
#pragma unroll
        for (int j = 0; j < 4; ++j) {
            int r = wave * 16 + lgrp * 4 + j;
            qrow[(size_t)r * 1024 + ocol] = (bf16_t)oacc[nf][j];
        }
    }
}

// ---------------- K4: output projection (r10 best config) -------------------
__global__ __launch_bounds__(256, 4) void proj_kernel(
    const bf16_t* __restrict__ a_g,   // [NTOK][1024] (cols 0..511 = O)
    const bf16_t* __restrict__ bt_g,  // proj_wt [512][512] (n-major)
    const float* __restrict__ bias,   // [512]
    float* __restrict__ out) {        // [NTOK][512] fp32
    __shared__ __align__(16) char sm_[32768];
    bf16_t* a_s = (bf16_t*)sm_;             // [128][64] swz8
    bf16_t* b_s = (bf16_t*)(sm_ + 16384);   // [128][64] swz8
    const int tid = threadIdx.x;
    const int wave = tid >> 6, lane = tid & 63;
    const int l31 = lane & 31, lhi = lane >> 5;
    const int wm = wave >> 1, wn = wave & 1;
    const int bid = blockIdx.x;                        // [0,2048)
    const int mtile = (bid & 7) * 64 + (bid >> 5);
    const int ntile = (bid >> 3) & 3;
    const size_t m0 = (size_t)mtile * 128;
    const int n0 = ntile * 128;
    const int srow = lane >> 3;
    const int scol = ((lane & 7) * 8) ^ ((srow & 7) << 3);

    f32x16 acc[2][2];
#pragma unroll
    for (int mf = 0; mf < 2; ++mf)
#pragma unroll
        for (int nf = 0; nf < 2; ++nf) acc[mf][nf] = (f32x16)0.0f;

#pragma unroll
    for (int kc = 0; kc < 8; ++kc) {
        const int k0 = kc * 64;
        __syncthreads();
#pragma unroll
        for (int i = 0; i < 4; ++i) {
            int c = wave * 4 + i;
            gload16(a_g + (m0 + c * 8 + srow) * 1024 + k0 + scol, a_s + c * 512);
            gload16(bt_g + (size_t)(n0 + c * 8 + srow) * 512 + k0 + scol, b_s + c * 512);
        }
        __syncthreads();

#pragma unroll
        for (int ks = 0; ks < 4; ++ks) {
            bf16x8 a[2], b[2];
#pragma unroll
            for (int mf = 0; mf < 2; ++mf) {
                int row = wm * 64 + mf * 32 + l31;
                a[mf] = *(const bf16x8*)(a_s + row * 64 +
                                         ((ks * 16 + lhi * 8) ^ ((row & 7) << 3)));
            }
#pragma unroll
            for (int nf = 0; nf < 2; ++nf) {
                int rw = wn * 64 + nf * 32 + l31;
                b[nf] = *(const bf16x8*)(b_s + rw * 64 +
                                         ((ks * 16 + lhi * 8) ^ ((rw & 7) << 3)));
            }
#pragma unroll
            for (int mf = 0; mf < 2; ++mf)
#pragma unroll
                for (int nf = 0; nf < 2; ++nf)
                    acc[mf][nf] = MFMA32(a[mf], b[nf], acc[mf][nf]);
        }
    }

#pragma unroll
    for (int nf = 0; nf < 2; ++nf) {
        int col = n0 + wn * 64 + nf * 32 + l31;
        float bv = bias[col];
#pragma unroll
        for (int mf = 0; mf < 2; ++mf)
#pragma unroll
            for (int j = 0; j < 16; ++j) {
                size_t row = m0 + wm * 64 + mf * 32 + (j & 3) + 8 * (j >> 2) + 4 * lhi;
                out[row * 512 + col] = acc[mf][nf][j] + bv;
            }
    }
}

extern "C" void kernel_launch(void* const* d_in, const int* in_sizes, int n_in,
                              void* d_out, int out_size, void* d_ws, size_t ws_size,
                              hipStream_t stream) {
    const float* x      = (const float*)d_in[0];
    const float* adj    = (const float*)d_in[1];
    const float* qkv_w  = (const float*)d_in[2];
    const float* qkv_b  = (const float*)d_in[3];
    const float* proj_w = (const float*)d_in[4];
    const float* proj_b = (const float*)d_in[5];
    float* out = (float*)d_out;

    // ws: qk_ws 134.2MB | vt_ws 67.1MB | qkv_wt 1.5MB | proj_wt 0.5MB
    bf16_t* qk_ws   = (bf16_t*)d_ws;
    bf16_t* vt_ws   = qk_ws + (size_t)NTOK * 1024;
    bf16_t* qkv_wt  = vt_ws + (size_t)4096 * 64 * 128;
    bf16_t* proj_wt = qkv_wt + 1536 * 512;
    // x-bf16 lives in d_out (64MB of its 128MB); proj overwrites d_out last.
    bf16_t* xbf = (bf16_t*)d_out;

    prep_all_kernel<<<NTOK * ED / 8 / 256, 256, 0, stream>>>(
        x, qkv_w, proj_w, xbf, qkv_wt, proj_wt);
    qkv_gemm_kernel<<<6144, 256, 0, stream>>>(xbf, qkv_wt, qkv_b, qk_ws, vt_ws);
    attn_kernel<<<4096, 512, 0, stream>>>(qk_ws, vt_ws, adj);
    proj_kernel<<<2048, 256, 0, stream>>>(qk_ws, proj_wt, proj_b, out);
}